// Round 3
// baseline (94.705 us; speedup 1.0000x reference)
//
#include <hip/hip_runtime.h>
#include <math.h>

// Tropical (max-plus) matmul: y[b,o] = max_i (x[b,i] + W[o,i])
// x: [512,1024] f32, W: [1024,1024] f32 (K-innermost), y: [512,1024] f32.
//
// R2 post-mortem: LDS-tile designs are LDS-pipe-bound at 1.5x the VALU floor
// (ds_read_b128 ~12cyc, one LDS pipe per CU shared by 4 SIMDs). R3 removes
// LDS from the K-loop entirely:
//   - wave owns 8 n-cols (W rows) -> wave-UNIFORM addresses -> s_load (SMEM)
//   - lane owns one m-row; x pre-transposed to xT[k][m] -> coalesced dword
//   - no __syncthreads in the K-loop; KS=8 split-K; 32 waves/CU.
// Exact: same fp32 adds as reference; max is order-free.

#define MDIM 512
#define NDIM 1024
#define KDIM 1024
#define NTHREADS 256
#define TN 8            // n-cols per wave
#define KS_DEF 8

// ---- x transpose: xT[k][m] = x[m][k] ----
__global__ __launch_bounds__(NTHREADS)
void transpose_x(const float* __restrict__ x, float* __restrict__ xT) {
    __shared__ float tile[32][33];
    const int k0 = blockIdx.x * 32;          // 32 k-tiles
    const int m0 = blockIdx.y * 32;          // 16 m-tiles
    const int tx = threadIdx.x & 31;
    const int ty = threadIdx.x >> 5;         // 0..7
#pragma unroll
    for (int i = 0; i < 4; ++i)
        tile[ty + i * 8][tx] = x[(size_t)(m0 + ty + i * 8) * KDIM + k0 + tx];
    __syncthreads();
#pragma unroll
    for (int i = 0; i < 4; ++i)
        xT[(size_t)(k0 + ty + i * 8) * MDIM + m0 + tx] = tile[tx][ty + i * 8];
}

// ---- main: each wave = 64 m-rows x 8 n-cols, K-slice of KC ----
__global__ __launch_bounds__(NTHREADS, 8)
void tropical_partial(const float* __restrict__ xT, const float* __restrict__ W,
                      float* __restrict__ ws, int KC) {
    const int lane = threadIdx.x & 63;
    const int wv   = threadIdx.x >> 6;            // 0..3
    const int mi   = blockIdx.x & 7;              // 8 m-strips of 64
    const int ni   = blockIdx.x >> 3;             // 32 n-strips of 32
    const int m0   = mi * 64;
    const int nc0  = ni * 32;
    const int nb   = nc0 + wv * TN;               // wave's first n
    const int k0   = blockIdx.y * KC;

    // wave-uniform W row pointers -> scalar loads
    const float* wr[TN];
#pragma unroll
    for (int j = 0; j < TN; ++j) {
        const int nu = __builtin_amdgcn_readfirstlane(nb + j);
        wr[j] = W + (size_t)nu * KDIM + k0;
    }
    const float* xp = xT + (size_t)k0 * MDIM + m0 + lane;

    float acc[TN];
#pragma unroll
    for (int j = 0; j < TN; ++j) acc[j] = -INFINITY;

    for (int kt = 0; kt < KC; kt += 8) {
        float a[8];
#pragma unroll
        for (int q = 0; q < 8; ++q)
            a[q] = xp[(size_t)(kt + q) * MDIM];       // coalesced dword, L1-shared
        float4 bv[TN][2];
#pragma unroll
        for (int j = 0; j < TN; ++j) {                // uniform -> s_load_dwordx4
            bv[j][0] = *(const float4*)(wr[j] + kt);
            bv[j][1] = *(const float4*)(wr[j] + kt + 4);
        }
#pragma unroll
        for (int j = 0; j < TN; ++j) {
            const float b[8] = {bv[j][0].x, bv[j][0].y, bv[j][0].z, bv[j][0].w,
                                bv[j][1].x, bv[j][1].y, bv[j][1].z, bv[j][1].w};
#pragma unroll
            for (int q = 0; q < 8; q += 2)            // 2 add + 1 v_max3 per 2k
                acc[j] = fmaxf(fmaxf(acc[j], a[q] + b[q]), a[q + 1] + b[q + 1]);
        }
    }

    // epilogue: LDS transpose for coalesced 128B-line stores
    __shared__ float st[64][33];
#pragma unroll
    for (int j = 0; j < TN; ++j) st[lane][wv * TN + j] = acc[j];
    __syncthreads();
    float* o = ws + (size_t)blockIdx.y * MDIM * NDIM;
    const int r  = threadIdx.x >> 2;            // 0..63 (row in tile)
    const int c8 = (threadIdx.x & 3) * 8;       // 0,8,16,24
    const float4 v0 = make_float4(st[r][c8 + 0], st[r][c8 + 1], st[r][c8 + 2], st[r][c8 + 3]);
    const float4 v1 = make_float4(st[r][c8 + 4], st[r][c8 + 5], st[r][c8 + 6], st[r][c8 + 7]);
    *(float4*)&o[(size_t)(m0 + r) * NDIM + nc0 + c8]     = v0;
    *(float4*)&o[(size_t)(m0 + r) * NDIM + nc0 + c8 + 4] = v1;
}

__global__ __launch_bounds__(NTHREADS)
void tropical_reduce(const float* __restrict__ ws, float* __restrict__ out, int KS) {
    const int i = blockIdx.x * NTHREADS + threadIdx.x;   // float4 index
    const int stride = MDIM * NDIM / 4;
    if (i >= stride) return;
    const float4* w4 = (const float4*)ws;
    float4 mv = w4[i];
    for (int s = 1; s < KS; ++s) {
        const float4 v = w4[(size_t)s * stride + i];
        mv.x = fmaxf(mv.x, v.x); mv.y = fmaxf(mv.y, v.y);
        mv.z = fmaxf(mv.z, v.z); mv.w = fmaxf(mv.w, v.w);
    }
    ((float4*)out)[i] = mv;
}

// correctness-only fallback if ws is tiny (not expected on this harness)
__global__ __launch_bounds__(NTHREADS)
void tropical_naive(const float* __restrict__ x, const float* __restrict__ W,
                    float* __restrict__ out) {
    const int idx = blockIdx.x * NTHREADS + threadIdx.x;
    const int m = idx >> 10, n = idx & 1023;
    float acc = -INFINITY;
    for (int k = 0; k < KDIM; ++k)
        acc = fmaxf(acc, x[(size_t)m * KDIM + k] + W[(size_t)n * KDIM + k]);
    out[idx] = acc;
}

extern "C" void kernel_launch(void* const* d_in, const int* in_sizes, int n_in,
                              void* d_out, int out_size, void* d_ws, size_t ws_size,
                              hipStream_t stream) {
    (void)in_sizes; (void)n_in; (void)out_size;
    const float* x = (const float*)d_in[0];
    const float* W = (const float*)d_in[1];
    float* out = (float*)d_out;
    float* ws  = (float*)d_ws;

    const size_t elems = (size_t)MDIM * NDIM;            // 2 MB / 524288 floats
    int KS = KS_DEF;
    while (KS > 1 && (1 + (size_t)KS) * elems * 4 > ws_size) KS >>= 1;

    if ((1 + (size_t)KS) * elems * 4 > ws_size) {
        tropical_naive<<<(int)(elems / NTHREADS), NTHREADS, 0, stream>>>(x, W, out);
        return;
    }

    float* xT     = ws;                                   // [1024][512]
    float* slices = ws + elems;                           // KS x [512][1024]

    transpose_x<<<dim3(KDIM / 32, MDIM / 32), NTHREADS, 0, stream>>>(x, xT);

    const int KC = KDIM / KS;                             // 128 at KS=8
    tropical_partial<<<dim3(256, KS), NTHREADS, 0, stream>>>(xT, W, slices, KC);

    tropical_reduce<<<(int)(elems / 4 / NTHREADS), NTHREADS, 0, stream>>>(slices, out, KS);
}